// Round 3
// baseline (228.146 us; speedup 1.0000x reference)
//
#include <hip/hip_runtime.h>
#include <hip/hip_bf16.h>

// Problem constants (fixed by the reference).
#define BB 32
#define SS 256
#define DD 256
#define UU 256
#define LL 16
#define DEG 16
#define NN (BB * SS)   // 8192 nodes
#define EE (NN * DEG)  // 131072 edges per branch
#define NSLICE 33      // slice 0 = self-loop, 1..16 = in labels, 17..32 = out labels
#define KMAIN (NSLICE * DD)   // 8448
#define KTOT  (KMAIN + 128)   // 8576 = 268*32 ; ext cols: wsum/bias GEMM trick
#define KSPLIT 4
#define KS (KTOT / KSPLIT)    // 2144 = 67*32

using short8 = __attribute__((ext_vector_type(8))) short;  // 8 bf16 (4 VGPRs)
using f32x4  = __attribute__((ext_vector_type(4))) float;  // MFMA accumulator

// async global->LDS, 16B per lane, LDS dest = wave-uniform base + lane*16
#define GLDS(g, l)                                                        \
  __builtin_amdgcn_global_load_lds(                                       \
      (const __attribute__((address_space(1))) void*)(g),                 \
      (__attribute__((address_space(3))) void*)(l), 16, 0, 0)

__device__ __forceinline__ float bf2f(unsigned short v) {
  union { unsigned u; float f; } t;
  t.u = ((unsigned)v) << 16;
  return t.f;
}
__device__ __forceinline__ float sigm(float x) {
  return 1.f / (1.f + __expf(-x));
}

// ---------------------------------------------------------------------------
// K1: x[n,d] = src[s,b,d] (n = b*S+s), cast to bf16; 3 gate dots in fp32.
// ---------------------------------------------------------------------------
__global__ __launch_bounds__(256) void k_prep(
    const float* __restrict__ src, const float* __restrict__ gin,
    const float* __restrict__ gout, const float* __restrict__ gloop,
    __hip_bfloat16* __restrict__ x_bf, float* __restrict__ xg_in,
    float* __restrict__ xg_out, float* __restrict__ xg_loop) {
  int n = blockIdx.x;
  int b = n / SS, s = n % SS;
  int d = threadIdx.x;
  float v = src[(size_t)(s * BB + b) * DD + d];
  x_bf[(size_t)n * DD + d] = __float2bfloat16(v);
  float p0 = v * gin[d], p1 = v * gout[d], p2 = v * gloop[d];
#pragma unroll
  for (int o = 32; o > 0; o >>= 1) {
    p0 += __shfl_down(p0, o);
    p1 += __shfl_down(p1, o);
    p2 += __shfl_down(p2, o);
  }
  __shared__ float r0[4], r1[4], r2[4];
  int w = threadIdx.x >> 6, lane = threadIdx.x & 63;
  if (lane == 0) { r0[w] = p0; r1[w] = p1; r2[w] = p2; }
  __syncthreads();
  if (threadIdx.x == 0) {
    xg_in[n]   = r0[0] + r0[1] + r0[2] + r0[3];
    xg_out[n]  = r1[0] + r1[1] + r1[2] + r1[3];
    xg_loop[n] = r2[0] + r2[1] + r2[2] + r2[3];
  }
}

// ---------------------------------------------------------------------------
// K2: transpose+cast weights into Vt[u][slice*256+d] = V[slice][d][u] (bf16).
// Row stride KTOT. slice 0 = W_self, 1..16 = V_in, 17..32 = V_out.
// ---------------------------------------------------------------------------
__global__ void k_transpose(const float* __restrict__ Vin,
                            const float* __restrict__ Vout,
                            const float* __restrict__ Wself,
                            __hip_bfloat16* __restrict__ Vt) {
  __shared__ float t[32][33];
  int z = blockIdx.z;
  const float* srcM = (z == 0) ? Wself
                    : (z <= LL ? Vin  + (size_t)(z - 1)      * DD * UU
                               : Vout + (size_t)(z - 1 - LL) * DD * UU);
  int u0 = blockIdx.x * 32, d0 = blockIdx.y * 32;
  int tx = threadIdx.x, ty = threadIdx.y;
#pragma unroll
  for (int i = 0; i < 4; i++) {
    int dr = ty + i * 8;
    t[dr][tx] = srcM[(size_t)(d0 + dr) * UU + u0 + tx];
  }
  __syncthreads();
#pragma unroll
  for (int i = 0; i < 4; i++) {
    int ur = ty + i * 8;
    Vt[(size_t)(u0 + ur) * KTOT + z * DD + d0 + tx] = __float2bfloat16(t[tx][ur]);
  }
}

// ---------------------------------------------------------------------------
// K2b: fill Vt ext rows (k = KMAIN..KTOT): Vt[u][KMAIN+j] = bias_all[j][u].
// j=0 self (no bias) -> 0; 1..16 b_in; 17..32 b_out; 33..127 pad 0.
// ---------------------------------------------------------------------------
__global__ __launch_bounds__(128) void k_biasfill(
    const float* __restrict__ b_in, const float* __restrict__ b_out,
    __hip_bfloat16* __restrict__ Vt) {
  int u = blockIdx.x, j = threadIdx.x;
  float v = 0.f;
  if (j >= 1 && j <= LL)       v = b_in[(j - 1) * UU + u];
  else if (j > LL && j < NSLICE) v = b_out[(j - 1 - LL) * UU + u];
  Vt[(size_t)u * KTOT + KMAIN + j] = __float2bfloat16(v);
}

// ---------------------------------------------------------------------------
// K3: aggregation. One block per dst node: Y[n][slice*256+d] = sum of gated
// x rows; ext cols = per-label gate-weight sums (for the bias GEMM trick).
// Ya columns are thread-private (thread tid owns d=tid) -> no barrier needed.
// ---------------------------------------------------------------------------
__global__ __launch_bounds__(256) void k_agg(
    const __hip_bfloat16* __restrict__ x,
    const float* __restrict__ xg_in, const float* __restrict__ xg_out,
    const float* __restrict__ xg_loop,
    const float* __restrict__ b_ing, const float* __restrict__ b_outg,
    const int* __restrict__ arc_in, const int* __restrict__ arc_out,
    const int* __restrict__ lab_in, const int* __restrict__ lab_out,
    const float* __restrict__ mask_in, const float* __restrict__ mask_out,
    const float* __restrict__ mask_loop,
    __hip_bfloat16* __restrict__ Y) {
  __shared__ float Ya[NSLICE][DD];   // 33 KB, column tid private to thread tid
  __shared__ int s_src[32];
  __shared__ int s_sl[32];
  __shared__ float s_w[32];
  __shared__ float s_wsum[NSLICE];
  int n = blockIdx.x, tid = threadIdx.x;
  if (tid < 32) {
    int br = tid >> 4, k = tid & 15;
    int e = n * DEG + k;
    const int* a = br ? arc_out : arc_in;
    int l = (br ? lab_out : lab_in)[e];
    int srcn = a[e] * SS + a[EE + e];
    float g = (br ? xg_out : xg_in)[srcn] + (br ? b_outg : b_ing)[l];
    s_src[tid] = srcn;
    s_sl[tid] = 1 + br * LL + l;
    s_w[tid] = sigm(g) * (br ? mask_out : mask_in)[e];
  }
  __syncthreads();
  // self-loop slice 0
  float wl = sigm(xg_loop[n]) * mask_loop[n];
  Ya[0][tid] = wl * bf2f(((const unsigned short*)x)[(size_t)n * DD + tid]);
#pragma unroll
  for (int i = 1; i < NSLICE; i++) Ya[i][tid] = 0.f;
#pragma unroll 4
  for (int k = 0; k < 32; k++) {
    float wv = s_w[k];
    float xv = bf2f(((const unsigned short*)x)[(size_t)s_src[k] * DD + tid]);
    Ya[s_sl[k]][tid] += wv * xv;
  }
  if (tid < NSLICE) {
    float ws = 0.f;
#pragma unroll
    for (int k = 0; k < 32; k++) ws += (s_sl[k] == tid) ? s_w[k] : 0.f;
    s_wsum[tid] = ws;  // tid 0 never matches -> 0 (self has no bias)
  }
  __syncthreads();
  size_t base = (size_t)n * KTOT;
#pragma unroll
  for (int i = 0; i < NSLICE; i++)
    Y[base + i * DD + tid] = __float2bfloat16(Ya[i][tid]);
  if (tid < 128)
    Y[base + KMAIN + tid] = __float2bfloat16(tid < NSLICE ? s_wsum[tid] : 0.f);
}

// ---------------------------------------------------------------------------
// K4: bf16 MFMA GEMM, m97 structure, split-K over blockIdx.z.
// partial[z][n][u] = sum_{k in z-th K-range} Y[n][k] * Vt[u][k]  (fp32).
// 128x128 tile, BK=32, 4 waves 2x2, each 4x4 frags of 16x16x32.
// ---------------------------------------------------------------------------
__global__ __launch_bounds__(256) void k_gemm(
    const __hip_bfloat16* __restrict__ A, const __hip_bfloat16* __restrict__ Bt,
    float* __restrict__ partial) {
  __shared__ __align__(16) __hip_bfloat16 As[128 * 32];
  __shared__ __align__(16) __hip_bfloat16 Bs[128 * 32];
  float* P = partial + (size_t)blockIdx.z * NN * UU;
  int kbeg = blockIdx.z * KS;

  int row0 = blockIdx.x * 128, col0 = blockIdx.y * 128;
  int tid = threadIdx.x;
  int w = tid >> 6, lane = tid & 63;
  int wr = (w >> 1) * 64, wc = (w & 1) * 64;
  int lrow = lane & 15, quad = lane >> 4;
  int sr = lane >> 2;          // staging: row within 16-row group
  int sc = (lane & 3) * 8;     // staging: k-offset (elements)

  f32x4 acc[4][4] = {};
  for (int k0 = kbeg; k0 < kbeg + KS; k0 += 32) {
#pragma unroll
    for (int t = 0; t < 2; t++) {
      int rb = (w * 2 + t) * 16;  // wave-uniform 16-row group
      GLDS(&A[(size_t)(row0 + rb + sr) * KTOT + k0 + sc], &As[rb * 32]);
      GLDS(&Bt[(size_t)(col0 + rb + sr) * KTOT + k0 + sc], &Bs[rb * 32]);
    }
    __syncthreads();
    short8 af[4], bfr[4];
#pragma unroll
    for (int i = 0; i < 4; i++)
      af[i] = *(const short8*)&As[(wr + i * 16 + lrow) * 32 + quad * 8];
#pragma unroll
    for (int j = 0; j < 4; j++)
      bfr[j] = *(const short8*)&Bs[(wc + j * 16 + lrow) * 32 + quad * 8];
#pragma unroll
    for (int i = 0; i < 4; i++)
#pragma unroll
      for (int j = 0; j < 4; j++)
        acc[i][j] = __builtin_amdgcn_mfma_f32_16x16x32_bf16(af[i], bfr[j], acc[i][j], 0, 0, 0);
    __syncthreads();
  }
  // C/D layout (m89/m91): col = lane&15, row = quad*4 + r
  // fp32 stores: 16 lanes x 4B = 64B full lines per quad -> coalesced.
#pragma unroll
  for (int i = 0; i < 4; i++)
#pragma unroll
    for (int j = 0; j < 4; j++) {
      int col = col0 + wc + j * 16 + lrow;
      int rowb = row0 + wr + i * 16 + quad * 4;
#pragma unroll
      for (int r = 0; r < 4; r++)
        P[(size_t)(rowb + r) * UU + col] = acc[i][j][r];
    }
}

// ---------------------------------------------------------------------------
// K5: reduce split-K partials + relu + sent_mask + transpose to out[s,b,u].
// ---------------------------------------------------------------------------
__global__ __launch_bounds__(64) void k_finish(const float* __restrict__ partial,
                                               const float* __restrict__ sent,
                                               float* __restrict__ out) {
  int n = blockIdx.x, u4 = threadIdx.x * 4;
  size_t idx = (size_t)n * UU + u4;
  float4 a = *(const float4*)&partial[idx];
#pragma unroll
  for (int z = 1; z < KSPLIT; z++) {
    float4 b = *(const float4*)&partial[(size_t)z * NN * UU + idx];
    a.x += b.x; a.y += b.y; a.z += b.z; a.w += b.w;
  }
  int s = n % SS, b = n / SS;
  float sm = sent[s * BB + b];
  float4 o;
  o.x = fmaxf(a.x, 0.f) * sm; o.y = fmaxf(a.y, 0.f) * sm;
  o.z = fmaxf(a.z, 0.f) * sm; o.w = fmaxf(a.w, 0.f) * sm;
  *(float4*)&out[((size_t)s * BB + b) * UU + u4] = o;
}

extern "C" void kernel_launch(void* const* d_in, const int* in_sizes, int n_in,
                              void* d_out, int out_size, void* d_ws, size_t ws_size,
                              hipStream_t stream) {
  const float* src      = (const float*)d_in[0];
  const float* V_in     = (const float*)d_in[1];
  const float* b_in     = (const float*)d_in[2];
  const float* V_ing    = (const float*)d_in[3];
  const float* b_ing    = (const float*)d_in[4];
  const float* V_out    = (const float*)d_in[5];
  const float* b_out    = (const float*)d_in[6];
  const float* V_outg   = (const float*)d_in[7];
  const float* b_outg   = (const float*)d_in[8];
  const float* W_self   = (const float*)d_in[9];
  const float* W_selfg  = (const float*)d_in[10];
  const int* arc_in     = (const int*)d_in[11];
  const int* arc_out    = (const int*)d_in[12];
  const int* lab_in     = (const int*)d_in[13];
  const int* lab_out    = (const int*)d_in[14];
  const float* mask_in  = (const float*)d_in[15];
  const float* mask_out = (const float*)d_in[16];
  const float* mask_loop= (const float*)d_in[17];
  const float* sent     = (const float*)d_in[18];
  float* out = (float*)d_out;

  char* ws = (char*)d_ws;
  size_t off = 0;
  auto alloc = [&](size_t bytes) -> void* {
    void* p = ws + off;
    off += (bytes + 255) & ~(size_t)255;
    return p;
  };
  __hip_bfloat16* x_bf = (__hip_bfloat16*)alloc((size_t)NN * DD * 2);       // 4 MB
  __hip_bfloat16* Vt   = (__hip_bfloat16*)alloc((size_t)UU * KTOT * 2);     // 4.4 MB
  float* xg_in   = (float*)alloc(NN * 4);
  float* xg_out  = (float*)alloc(NN * 4);
  float* xg_loop = (float*)alloc(NN * 4);
  __hip_bfloat16* Y = (__hip_bfloat16*)alloc((size_t)NN * KTOT * 2);        // 140 MB
  float* partial = (float*)alloc((size_t)KSPLIT * NN * UU * 4);             // 33.6 MB

  k_prep<<<NN, 256, 0, stream>>>(src, V_ing, V_outg, W_selfg, x_bf, xg_in, xg_out, xg_loop);
  k_transpose<<<dim3(UU / 32, DD / 32, NSLICE), dim3(32, 8), 0, stream>>>(
      V_in, V_out, W_self, Vt);
  k_biasfill<<<UU, 128, 0, stream>>>(b_in, b_out, Vt);
  k_agg<<<NN, 256, 0, stream>>>(x_bf, xg_in, xg_out, xg_loop, b_ing, b_outg,
                                arc_in, arc_out, lab_in, lab_out,
                                mask_in, mask_out, mask_loop, Y);
  k_gemm<<<dim3(NN / 128, UU / 128, KSPLIT), 256, 0, stream>>>(Y, Vt, partial);
  k_finish<<<NN, 64, 0, stream>>>(partial, sent, out);
}

// Round 4
// 211.616 us; speedup vs baseline: 1.0781x; 1.0781x over previous
//
#include <hip/hip_runtime.h>
#include <hip/hip_bf16.h>

// Problem constants (fixed by the reference).
#define BB 32
#define SS 256
#define DD 256
#define UU 256
#define LL 16
#define DEG 16
#define NN (BB * SS)   // 8192 nodes
#define EE (NN * DEG)  // 131072 edges per branch
#define NSLICE 33      // slice 0 = self-loop, 1..16 = in labels, 17..32 = out labels
#define KMAIN (NSLICE * DD)   // 8448
#define KEXT 256              // ext cols: wsum/bias GEMM trick (33 used, rest 0)
#define KTOT (KMAIN + KEXT)   // 8704 = 34*256
#define KSPLIT 8
#define KS (KTOT / KSPLIT)    // 1088 = 34*32

using short8 = __attribute__((ext_vector_type(8))) short;  // 8 bf16 (4 VGPRs)
using f32x4  = __attribute__((ext_vector_type(4))) float;  // MFMA accumulator

// async global->LDS, 16B per lane, LDS dest = wave-uniform base + lane*16
#define GLDS(g, l)                                                        \
  __builtin_amdgcn_global_load_lds(                                       \
      (const __attribute__((address_space(1))) void*)(g),                 \
      (__attribute__((address_space(3))) void*)(l), 16, 0, 0)

__device__ __forceinline__ float bf2f(unsigned short v) {
  union { unsigned u; float f; } t;
  t.u = ((unsigned)v) << 16;
  return t.f;
}
__device__ __forceinline__ unsigned short f2bf(float f) {
  __hip_bfloat16 h = __float2bfloat16(f);
  return *(unsigned short*)&h;
}
__device__ __forceinline__ float sigm(float x) {
  return 1.f / (1.f + __expf(-x));
}

// ---------------------------------------------------------------------------
// K1: x[n,d] = src[s,b,d] (n = b*S+s), cast to bf16; 3 gate dots in fp32.
// ---------------------------------------------------------------------------
__global__ __launch_bounds__(256) void k_prep(
    const float* __restrict__ src, const float* __restrict__ gin,
    const float* __restrict__ gout, const float* __restrict__ gloop,
    __hip_bfloat16* __restrict__ x_bf, float* __restrict__ xg_in,
    float* __restrict__ xg_out, float* __restrict__ xg_loop) {
  int n = blockIdx.x;
  int b = n / SS, s = n % SS;
  int d = threadIdx.x;
  float v = src[(size_t)(s * BB + b) * DD + d];
  x_bf[(size_t)n * DD + d] = __float2bfloat16(v);
  float p0 = v * gin[d], p1 = v * gout[d], p2 = v * gloop[d];
#pragma unroll
  for (int o = 32; o > 0; o >>= 1) {
    p0 += __shfl_down(p0, o);
    p1 += __shfl_down(p1, o);
    p2 += __shfl_down(p2, o);
  }
  __shared__ float r0[4], r1[4], r2[4];
  int w = threadIdx.x >> 6, lane = threadIdx.x & 63;
  if (lane == 0) { r0[w] = p0; r1[w] = p1; r2[w] = p2; }
  __syncthreads();
  if (threadIdx.x == 0) {
    xg_in[n]   = r0[0] + r0[1] + r0[2] + r0[3];
    xg_out[n]  = r1[0] + r1[1] + r1[2] + r1[3];
    xg_loop[n] = r2[0] + r2[1] + r2[2] + r2[3];
  }
}

// ---------------------------------------------------------------------------
// K2: transpose+cast weights into Vt[u][slice*256+d] = V[slice][d][u] (bf16).
// Row stride KTOT. slice 0 = W_self, 1..16 = V_in, 17..32 = V_out.
// ---------------------------------------------------------------------------
__global__ void k_transpose(const float* __restrict__ Vin,
                            const float* __restrict__ Vout,
                            const float* __restrict__ Wself,
                            __hip_bfloat16* __restrict__ Vt) {
  __shared__ float t[32][33];
  int z = blockIdx.z;
  const float* srcM = (z == 0) ? Wself
                    : (z <= LL ? Vin  + (size_t)(z - 1)      * DD * UU
                               : Vout + (size_t)(z - 1 - LL) * DD * UU);
  int u0 = blockIdx.x * 32, d0 = blockIdx.y * 32;
  int tx = threadIdx.x, ty = threadIdx.y;
#pragma unroll
  for (int i = 0; i < 4; i++) {
    int dr = ty + i * 8;
    t[dr][tx] = srcM[(size_t)(d0 + dr) * UU + u0 + tx];
  }
  __syncthreads();
#pragma unroll
  for (int i = 0; i < 4; i++) {
    int ur = ty + i * 8;
    Vt[(size_t)(u0 + ur) * KTOT + z * DD + d0 + tx] = __float2bfloat16(t[tx][ur]);
  }
}

// ---------------------------------------------------------------------------
// K2b: fill Vt ext rows (k = KMAIN..KTOT): Vt[u][KMAIN+j] = bias_all[j][u].
// j=0 self (no bias) -> 0; 1..16 b_in; 17..32 b_out; 33..255 pad 0.
// ---------------------------------------------------------------------------
__global__ __launch_bounds__(256) void k_biasfill(
    const float* __restrict__ b_in, const float* __restrict__ b_out,
    __hip_bfloat16* __restrict__ Vt) {
  int u = blockIdx.x, j = threadIdx.x;
  float v = 0.f;
  if (j >= 1 && j <= LL)           v = b_in[(j - 1) * UU + u];
  else if (j > LL && j < NSLICE)   v = b_out[(j - 1 - LL) * UU + u];
  Vt[(size_t)u * KTOT + KMAIN + j] = __float2bfloat16(v);
}

// ---------------------------------------------------------------------------
// K3: aggregation, one WAVE (64 threads) per dst node, register accumulators.
// Edges rank-sorted by slice; slice-major sweep writes each Y row once.
// Y[n][slice*256+d] = sum of gated x rows; ext col j = per-slice weight sum.
// ---------------------------------------------------------------------------
__global__ __launch_bounds__(64) void k_agg(
    const __hip_bfloat16* __restrict__ x,
    const float* __restrict__ xg_in, const float* __restrict__ xg_out,
    const float* __restrict__ xg_loop,
    const float* __restrict__ b_ing, const float* __restrict__ b_outg,
    const int* __restrict__ arc_in, const int* __restrict__ arc_out,
    const int* __restrict__ lab_in, const int* __restrict__ lab_out,
    const float* __restrict__ mask_in, const float* __restrict__ mask_out,
    const float* __restrict__ mask_loop,
    __hip_bfloat16* __restrict__ Y) {
  __shared__ int u_sl[32], u_src[32];
  __shared__ float u_w[32];
  __shared__ int s_sl[32], s_src[32];
  __shared__ float s_w[32];
  __shared__ float s_wsum[NSLICE];
  int n = blockIdx.x, tid = threadIdx.x;
  if (tid < 32) {
    int br = tid >> 4, k = tid & 15;
    int e = n * DEG + k;
    const int* a = br ? arc_out : arc_in;
    int l = (br ? lab_out : lab_in)[e];
    int srcn = a[e] * SS + a[EE + e];
    float g = (br ? xg_out : xg_in)[srcn] + (br ? b_outg : b_ing)[l];
    u_sl[tid] = 1 + br * LL + l;
    u_src[tid] = srcn;
    u_w[tid] = sigm(g) * (br ? mask_out : mask_in)[e];
  }
  __syncthreads();
  if (tid < 32) {
    int my = u_sl[tid];
    int rank = 0;
#pragma unroll
    for (int j = 0; j < 32; j++) {
      int oj = u_sl[j];
      rank += (oj < my || (oj == my && j < tid)) ? 1 : 0;
    }
    s_sl[rank] = my;
    s_src[rank] = u_src[tid];
    s_w[rank] = u_w[tid];
  }
  __syncthreads();

  const unsigned short* xp = (const unsigned short*)x;
  size_t base = (size_t)n * KTOT;
  int d4 = tid * 4;
  // slice 0: self-loop
  {
    float wl = sigm(xg_loop[n]) * mask_loop[n];
    ushort4 v = *(const ushort4*)&xp[(size_t)n * DD + d4];
    ushort4 o;
    o.x = f2bf(wl * bf2f(v.x)); o.y = f2bf(wl * bf2f(v.y));
    o.z = f2bf(wl * bf2f(v.z)); o.w = f2bf(wl * bf2f(v.w));
    *(ushort4*)&((unsigned short*)Y)[base + d4] = o;
  }
  // slices 1..32: sweep sorted edge list (uniform control flow)
  int ptr = 0;
  for (int s = 1; s < NSLICE; s++) {
    float a0 = 0.f, a1 = 0.f, a2 = 0.f, a3 = 0.f, ws = 0.f;
    while (ptr < 32 && s_sl[ptr] == s) {
      int srcn = s_src[ptr];
      float w = s_w[ptr];
      ushort4 v = *(const ushort4*)&xp[(size_t)srcn * DD + d4];
      a0 += w * bf2f(v.x); a1 += w * bf2f(v.y);
      a2 += w * bf2f(v.z); a3 += w * bf2f(v.w);
      ws += w;
      ptr++;
    }
    ushort4 o;
    o.x = f2bf(a0); o.y = f2bf(a1); o.z = f2bf(a2); o.w = f2bf(a3);
    *(ushort4*)&((unsigned short*)Y)[base + s * DD + d4] = o;
    if (tid == 0) s_wsum[s] = ws;
  }
  __syncthreads();
  // ext cols: j in [0,256): wsum for 1..32, else 0
  {
    ushort4 o;
    unsigned short* op = (unsigned short*)&o;
#pragma unroll
    for (int c = 0; c < 4; c++) {
      int j = d4 + c;
      float v = (j >= 1 && j < NSLICE) ? s_wsum[j] : 0.f;
      op[c] = f2bf(v);
    }
    *(ushort4*)&((unsigned short*)Y)[base + KMAIN + d4] = o;
  }
}

// ---------------------------------------------------------------------------
// K4: bf16 MFMA GEMM, m97 structure, split-K over blockIdx.z (KSPLIT=8 ->
// 1024 blocks, 4 blocks/CU). partial[z][n][u] (bf16) = partial dot.
// 128x128 tile, BK=32, 4 waves 2x2, each 4x4 frags of 16x16x32.
// ---------------------------------------------------------------------------
__global__ __launch_bounds__(256) void k_gemm(
    const __hip_bfloat16* __restrict__ A, const __hip_bfloat16* __restrict__ Bt,
    __hip_bfloat16* __restrict__ partial) {
  __shared__ __align__(16) __hip_bfloat16 As[128 * 32];
  __shared__ __align__(16) __hip_bfloat16 Bs[128 * 32];
  __hip_bfloat16* P = partial + (size_t)blockIdx.z * NN * UU;
  int kbeg = blockIdx.z * KS;

  int row0 = blockIdx.x * 128, col0 = blockIdx.y * 128;
  int tid = threadIdx.x;
  int w = tid >> 6, lane = tid & 63;
  int wr = (w >> 1) * 64, wc = (w & 1) * 64;
  int lrow = lane & 15, quad = lane >> 4;
  int sr = lane >> 2;          // staging: row within 16-row group
  int sc = (lane & 3) * 8;     // staging: k-offset (elements)

  f32x4 acc[4][4] = {};
  for (int k0 = kbeg; k0 < kbeg + KS; k0 += 32) {
#pragma unroll
    for (int t = 0; t < 2; t++) {
      int rb = (w * 2 + t) * 16;  // wave-uniform 16-row group
      GLDS(&A[(size_t)(row0 + rb + sr) * KTOT + k0 + sc], &As[rb * 32]);
      GLDS(&Bt[(size_t)(col0 + rb + sr) * KTOT + k0 + sc], &Bs[rb * 32]);
    }
    __syncthreads();
    short8 af[4], bfr[4];
#pragma unroll
    for (int i = 0; i < 4; i++)
      af[i] = *(const short8*)&As[(wr + i * 16 + lrow) * 32 + quad * 8];
#pragma unroll
    for (int j = 0; j < 4; j++)
      bfr[j] = *(const short8*)&Bs[(wc + j * 16 + lrow) * 32 + quad * 8];
#pragma unroll
    for (int i = 0; i < 4; i++)
#pragma unroll
      for (int j = 0; j < 4; j++)
        acc[i][j] = __builtin_amdgcn_mfma_f32_16x16x32_bf16(af[i], bfr[j], acc[i][j], 0, 0, 0);
    __syncthreads();
  }
  // C/D layout (m89/m91): col = lane&15, row = quad*4 + r
#pragma unroll
  for (int i = 0; i < 4; i++)
#pragma unroll
    for (int j = 0; j < 4; j++) {
      int col = col0 + wc + j * 16 + lrow;
      int rowb = row0 + wr + i * 16 + quad * 4;
#pragma unroll
      for (int r = 0; r < 4; r++)
        P[(size_t)(rowb + r) * UU + col] = __float2bfloat16(acc[i][j][r]);
    }
}

// ---------------------------------------------------------------------------
// K5: reduce KSPLIT bf16 partials + relu + sent_mask + transpose to out[s,b,u].
// Partial buffer is 34 MB total -> L2/L3-resident.
// ---------------------------------------------------------------------------
__global__ __launch_bounds__(64) void k_finish(
    const __hip_bfloat16* __restrict__ partial, const float* __restrict__ sent,
    float* __restrict__ out) {
  int n = blockIdx.x, u4 = threadIdx.x * 4;
  size_t idx = (size_t)n * UU + u4;
  const unsigned short* pp = (const unsigned short*)partial;
  float a0 = 0.f, a1 = 0.f, a2 = 0.f, a3 = 0.f;
#pragma unroll
  for (int z = 0; z < KSPLIT; z++) {
    ushort4 v = *(const ushort4*)&pp[(size_t)z * NN * UU + idx];
    a0 += bf2f(v.x); a1 += bf2f(v.y); a2 += bf2f(v.z); a3 += bf2f(v.w);
  }
  int s = n % SS, b = n / SS;
  float sm = sent[s * BB + b];
  float4 o;
  o.x = fmaxf(a0, 0.f) * sm; o.y = fmaxf(a1, 0.f) * sm;
  o.z = fmaxf(a2, 0.f) * sm; o.w = fmaxf(a3, 0.f) * sm;
  *(float4*)&out[((size_t)s * BB + b) * UU + u4] = o;
}

extern "C" void kernel_launch(void* const* d_in, const int* in_sizes, int n_in,
                              void* d_out, int out_size, void* d_ws, size_t ws_size,
                              hipStream_t stream) {
  const float* src      = (const float*)d_in[0];
  const float* V_in     = (const float*)d_in[1];
  const float* b_in     = (const float*)d_in[2];
  const float* V_ing    = (const float*)d_in[3];
  const float* b_ing    = (const float*)d_in[4];
  const float* V_out    = (const float*)d_in[5];
  const float* b_out    = (const float*)d_in[6];
  const float* V_outg   = (const float*)d_in[7];
  const float* b_outg   = (const float*)d_in[8];
  const float* W_self   = (const float*)d_in[9];
  const float* W_selfg  = (const float*)d_in[10];
  const int* arc_in     = (const int*)d_in[11];
  const int* arc_out    = (const int*)d_in[12];
  const int* lab_in     = (const int*)d_in[13];
  const int* lab_out    = (const int*)d_in[14];
  const float* mask_in  = (const float*)d_in[15];
  const float* mask_out = (const float*)d_in[16];
  const float* mask_loop= (const float*)d_in[17];
  const float* sent     = (const float*)d_in[18];
  float* out = (float*)d_out;

  char* ws = (char*)d_ws;
  size_t off = 0;
  auto alloc = [&](size_t bytes) -> void* {
    void* p = ws + off;
    off += (bytes + 255) & ~(size_t)255;
    return p;
  };
  __hip_bfloat16* x_bf = (__hip_bfloat16*)alloc((size_t)NN * DD * 2);       // 4 MB
  __hip_bfloat16* Vt   = (__hip_bfloat16*)alloc((size_t)UU * KTOT * 2);     // 4.5 MB
  float* xg_in   = (float*)alloc(NN * 4);
  float* xg_out  = (float*)alloc(NN * 4);
  float* xg_loop = (float*)alloc(NN * 4);
  __hip_bfloat16* Y = (__hip_bfloat16*)alloc((size_t)NN * KTOT * 2);        // 143 MB
  __hip_bfloat16* partial =
      (__hip_bfloat16*)alloc((size_t)KSPLIT * NN * UU * 2);                 // 34 MB

  k_prep<<<NN, 256, 0, stream>>>(src, V_ing, V_outg, W_selfg, x_bf, xg_in, xg_out, xg_loop);
  k_transpose<<<dim3(UU / 32, DD / 32, NSLICE), dim3(32, 8), 0, stream>>>(
      V_in, V_out, W_self, Vt);
  k_biasfill<<<UU, 256, 0, stream>>>(b_in, b_out, Vt);
  k_agg<<<NN, 64, 0, stream>>>(x_bf, xg_in, xg_out, xg_loop, b_ing, b_outg,
                               arc_in, arc_out, lab_in, lab_out,
                               mask_in, mask_out, mask_loop, Y);
  k_gemm<<<dim3(NN / 128, UU / 128, KSPLIT), 256, 0, stream>>>(Y, Vt, partial);
  k_finish<<<NN, 64, 0, stream>>>(partial, sent, out);
}

// Round 5
// 210.854 us; speedup vs baseline: 1.0820x; 1.0036x over previous
//
#include <hip/hip_runtime.h>
#include <hip/hip_bf16.h>

// Problem constants (fixed by the reference).
#define BB 32
#define SS 256
#define DD 256
#define UU 256
#define LL 16
#define DEG 16
#define NN (BB * SS)   // 8192 nodes
#define EE (NN * DEG)  // 131072 edges per branch
#define NSLICE 33      // slice 0 = self-loop, 1..16 = in labels, 17..32 = out labels
#define KMAIN (NSLICE * DD)   // 8448
#define KEXT 256              // ext cols: wsum/bias GEMM trick (33 used, rest 0)
#define KTOT (KMAIN + KEXT)   // 8704 = 34*256
#define KSPLIT 8
#define KS (KTOT / KSPLIT)    // 1088 = 34*32

using short8 = __attribute__((ext_vector_type(8))) short;  // 8 bf16 (4 VGPRs)
using f32x4  = __attribute__((ext_vector_type(4))) float;  // MFMA accumulator

// async global->LDS, 16B per lane, LDS dest = wave-uniform base + lane*16
#define GLDS(g, l)                                                        \
  __builtin_amdgcn_global_load_lds(                                       \
      (const __attribute__((address_space(1))) void*)(g),                 \
      (__attribute__((address_space(3))) void*)(l), 16, 0, 0)

__device__ __forceinline__ float bf2f(unsigned short v) {
  union { unsigned u; float f; } t;
  t.u = ((unsigned)v) << 16;
  return t.f;
}
__device__ __forceinline__ unsigned short f2bf(float f) {
  __hip_bfloat16 h = __float2bfloat16(f);
  return *(unsigned short*)&h;
}
__device__ __forceinline__ float sigm(float x) {
  return 1.f / (1.f + __expf(-x));
}

// ---------------------------------------------------------------------------
// K1: x[n,d] = src[s,b,d] (n = b*S+s), cast to bf16; 3 gate dots in fp32.
// ---------------------------------------------------------------------------
__global__ __launch_bounds__(256) void k_prep(
    const float* __restrict__ src, const float* __restrict__ gin,
    const float* __restrict__ gout, const float* __restrict__ gloop,
    __hip_bfloat16* __restrict__ x_bf, float* __restrict__ xg_in,
    float* __restrict__ xg_out, float* __restrict__ xg_loop) {
  int n = blockIdx.x;
  int b = n / SS, s = n % SS;
  int d = threadIdx.x;
  float v = src[(size_t)(s * BB + b) * DD + d];
  x_bf[(size_t)n * DD + d] = __float2bfloat16(v);
  float p0 = v * gin[d], p1 = v * gout[d], p2 = v * gloop[d];
#pragma unroll
  for (int o = 32; o > 0; o >>= 1) {
    p0 += __shfl_down(p0, o);
    p1 += __shfl_down(p1, o);
    p2 += __shfl_down(p2, o);
  }
  __shared__ float r0[4], r1[4], r2[4];
  int w = threadIdx.x >> 6, lane = threadIdx.x & 63;
  if (lane == 0) { r0[w] = p0; r1[w] = p1; r2[w] = p2; }
  __syncthreads();
  if (threadIdx.x == 0) {
    xg_in[n]   = r0[0] + r0[1] + r0[2] + r0[3];
    xg_out[n]  = r1[0] + r1[1] + r1[2] + r1[3];
    xg_loop[n] = r2[0] + r2[1] + r2[2] + r2[3];
  }
}

// ---------------------------------------------------------------------------
// K2: transpose+cast weights into Vt[u][slice*256+d] = V[slice][d][u] (bf16).
// z in [0,NSLICE): transpose; z == NSLICE: fill ext bias rows
// Vt[u][KMAIN+j] = bias_all[j][u] (j=0 self -> 0; 1..16 b_in; 17..32 b_out).
// ---------------------------------------------------------------------------
__global__ void k_transpose(const float* __restrict__ Vin,
                            const float* __restrict__ Vout,
                            const float* __restrict__ Wself,
                            const float* __restrict__ b_in,
                            const float* __restrict__ b_out,
                            __hip_bfloat16* __restrict__ Vt) {
  int z = blockIdx.z;
  int tx = threadIdx.x, ty = threadIdx.y;
  if (z == NSLICE) {
    int u0 = blockIdx.x * 32, j0 = blockIdx.y * 32;
#pragma unroll
    for (int i = 0; i < 4; i++) {
      int u = u0 + ty + i * 8, j = j0 + tx;
      float v = 0.f;
      if (j >= 1 && j <= LL)         v = b_in[(j - 1) * UU + u];
      else if (j > LL && j < NSLICE) v = b_out[(j - 1 - LL) * UU + u];
      Vt[(size_t)u * KTOT + KMAIN + j] = __float2bfloat16(v);
    }
    return;
  }
  __shared__ float t[32][33];
  const float* srcM = (z == 0) ? Wself
                    : (z <= LL ? Vin  + (size_t)(z - 1)      * DD * UU
                               : Vout + (size_t)(z - 1 - LL) * DD * UU);
  int u0 = blockIdx.x * 32, d0 = blockIdx.y * 32;
#pragma unroll
  for (int i = 0; i < 4; i++) {
    int dr = ty + i * 8;
    t[dr][tx] = srcM[(size_t)(d0 + dr) * UU + u0 + tx];
  }
  __syncthreads();
#pragma unroll
  for (int i = 0; i < 4; i++) {
    int ur = ty + i * 8;
    Vt[(size_t)(u0 + ur) * KTOT + z * DD + d0 + tx] = __float2bfloat16(t[tx][ur]);
  }
}

// ---------------------------------------------------------------------------
// K3: aggregation, one WAVE per dst node. Rank-sort edges by slice once, then
// a FLAT fully-unrolled 32-edge sweep (no LDS pointer-chase: metadata loads
// use immediate offsets, so all x-row gathers pipeline). Slice boundaries
// (uniform branch) flush the register accumulator; absent slices zero-filled
// from a bitmask. Y[n][slice*256+d]; ext col j = per-slice gate-weight sum.
// ---------------------------------------------------------------------------
__global__ __launch_bounds__(64) void k_agg(
    const __hip_bfloat16* __restrict__ x,
    const float* __restrict__ xg_in, const float* __restrict__ xg_out,
    const float* __restrict__ xg_loop,
    const float* __restrict__ b_ing, const float* __restrict__ b_outg,
    const int* __restrict__ arc_in, const int* __restrict__ arc_out,
    const int* __restrict__ lab_in, const int* __restrict__ lab_out,
    const float* __restrict__ mask_in, const float* __restrict__ mask_out,
    const float* __restrict__ mask_loop,
    __hip_bfloat16* __restrict__ Y) {
  __shared__ int u_sl[32], u_src[32];
  __shared__ float u_w[32];
  __shared__ int s_sl[32], s_src[32];
  __shared__ float s_w[32];
  __shared__ float s_wsum[NSLICE];
  int n = blockIdx.x, tid = threadIdx.x;
  if (tid < 32) {
    int br = tid >> 4, k = tid & 15;
    int e = n * DEG + k;
    const int* a = br ? arc_out : arc_in;
    int l = (br ? lab_out : lab_in)[e];
    int srcn = a[e] * SS + a[EE + e];
    float g = (br ? xg_out : xg_in)[srcn] + (br ? b_outg : b_ing)[l];
    u_sl[tid] = 1 + br * LL + l;
    u_src[tid] = srcn;
    u_w[tid] = sigm(g) * (br ? mask_out : mask_in)[e];
  }
  __syncthreads();
  if (tid < 32) {
    int my = u_sl[tid];
    int rank = 0;
#pragma unroll
    for (int j = 0; j < 32; j++) {
      int oj = u_sl[j];
      rank += (oj < my || (oj == my && j < tid)) ? 1 : 0;
    }
    s_sl[rank] = my;
    s_src[rank] = u_src[tid];
    s_w[rank] = u_w[tid];
  }
  __syncthreads();

  const unsigned short* xp = (const unsigned short*)x;
  unsigned short* yp = (unsigned short*)Y;
  size_t base = (size_t)n * KTOT;
  int d4 = tid * 4;
  // slice 0: self-loop
  {
    float wl = sigm(xg_loop[n]) * mask_loop[n];
    ushort4 v = *(const ushort4*)&xp[(size_t)n * DD + d4];
    ushort4 o;
    o.x = f2bf(wl * bf2f(v.x)); o.y = f2bf(wl * bf2f(v.y));
    o.z = f2bf(wl * bf2f(v.z)); o.w = f2bf(wl * bf2f(v.w));
    *(ushort4*)&yp[base + d4] = o;
  }
  // flat sweep over 32 sorted edges
  unsigned long long present = 0ull;
  float a0 = 0.f, a1 = 0.f, a2 = 0.f, a3 = 0.f, ws = 0.f;
#pragma unroll
  for (int e = 0; e < 32; e++) {
    int sl = s_sl[e];            // imm-offset LDS loads: no chase
    int srcn = s_src[e];
    float w = s_w[e];
    ushort4 v = *(const ushort4*)&xp[(size_t)srcn * DD + d4];
    a0 += w * bf2f(v.x); a1 += w * bf2f(v.y);
    a2 += w * bf2f(v.z); a3 += w * bf2f(v.w);
    ws += w;
    int slnext = (e < 31) ? s_sl[e + 1] : 999;
    if (sl != slnext) {          // uniform branch (LDS values identical/lane)
      ushort4 o;
      o.x = f2bf(a0); o.y = f2bf(a1); o.z = f2bf(a2); o.w = f2bf(a3);
      *(ushort4*)&yp[base + sl * DD + d4] = o;
      if (tid == 0) s_wsum[sl] = ws;
      present |= (1ull << sl);
      a0 = a1 = a2 = a3 = ws = 0.f;
    }
  }
  // zero-fill absent slices
  ushort4 zero4 = {0, 0, 0, 0};
#pragma unroll
  for (int s = 1; s < NSLICE; s++) {
    if (!((present >> s) & 1ull)) {
      *(ushort4*)&yp[base + s * DD + d4] = zero4;
      if (tid == 0) s_wsum[s] = 0.f;
    }
  }
  __syncthreads();
  // ext cols: j in [0,256): wsum for 1..32, else 0
  {
    ushort4 o;
    unsigned short* op = (unsigned short*)&o;
#pragma unroll
    for (int c = 0; c < 4; c++) {
      int j = d4 + c;
      float v = (j >= 1 && j < NSLICE) ? s_wsum[j] : 0.f;
      op[c] = f2bf(v);
    }
    *(ushort4*)&yp[base + KMAIN + d4] = o;
  }
}

// ---------------------------------------------------------------------------
// K4: bf16 MFMA GEMM, m97 structure, split-K over blockIdx.z (KSPLIT=8 ->
// 1024 blocks). partial[z][n][u] (bf16). 128x128 tile, BK=32, 4 waves 2x2,
// each 4x4 frags of 16x16x32.
// ---------------------------------------------------------------------------
__global__ __launch_bounds__(256) void k_gemm(
    const __hip_bfloat16* __restrict__ A, const __hip_bfloat16* __restrict__ Bt,
    __hip_bfloat16* __restrict__ partial) {
  __shared__ __align__(16) __hip_bfloat16 As[128 * 32];
  __shared__ __align__(16) __hip_bfloat16 Bs[128 * 32];
  __hip_bfloat16* P = partial + (size_t)blockIdx.z * NN * UU;
  int kbeg = blockIdx.z * KS;

  int row0 = blockIdx.x * 128, col0 = blockIdx.y * 128;
  int tid = threadIdx.x;
  int w = tid >> 6, lane = tid & 63;
  int wr = (w >> 1) * 64, wc = (w & 1) * 64;
  int lrow = lane & 15, quad = lane >> 4;
  int sr = lane >> 2;          // staging: row within 16-row group
  int sc = (lane & 3) * 8;     // staging: k-offset (elements)

  f32x4 acc[4][4] = {};
  for (int k0 = kbeg; k0 < kbeg + KS; k0 += 32) {
#pragma unroll
    for (int t = 0; t < 2; t++) {
      int rb = (w * 2 + t) * 16;  // wave-uniform 16-row group
      GLDS(&A[(size_t)(row0 + rb + sr) * KTOT + k0 + sc], &As[rb * 32]);
      GLDS(&Bt[(size_t)(col0 + rb + sr) * KTOT + k0 + sc], &Bs[rb * 32]);
    }
    __syncthreads();
    short8 af[4], bfr[4];
#pragma unroll
    for (int i = 0; i < 4; i++)
      af[i] = *(const short8*)&As[(wr + i * 16 + lrow) * 32 + quad * 8];
#pragma unroll
    for (int j = 0; j < 4; j++)
      bfr[j] = *(const short8*)&Bs[(wc + j * 16 + lrow) * 32 + quad * 8];
#pragma unroll
    for (int i = 0; i < 4; i++)
#pragma unroll
      for (int j = 0; j < 4; j++)
        acc[i][j] = __builtin_amdgcn_mfma_f32_16x16x32_bf16(af[i], bfr[j], acc[i][j], 0, 0, 0);
    __syncthreads();
  }
  // C/D layout (m89/m91): col = lane&15, row = quad*4 + r
#pragma unroll
  for (int i = 0; i < 4; i++)
#pragma unroll
    for (int j = 0; j < 4; j++) {
      int col = col0 + wc + j * 16 + lrow;
      int rowb = row0 + wr + i * 16 + quad * 4;
#pragma unroll
      for (int r = 0; r < 4; r++)
        P[(size_t)(rowb + r) * UU + col] = __float2bfloat16(acc[i][j][r]);
    }
}

// ---------------------------------------------------------------------------
// K5: reduce KSPLIT bf16 partials + relu + sent_mask + transpose to out[s,b,u].
// ---------------------------------------------------------------------------
__global__ __launch_bounds__(64) void k_finish(
    const __hip_bfloat16* __restrict__ partial, const float* __restrict__ sent,
    float* __restrict__ out) {
  int n = blockIdx.x, u4 = threadIdx.x * 4;
  size_t idx = (size_t)n * UU + u4;
  const unsigned short* pp = (const unsigned short*)partial;
  float a0 = 0.f, a1 = 0.f, a2 = 0.f, a3 = 0.f;
#pragma unroll
  for (int z = 0; z < KSPLIT; z++) {
    ushort4 v = *(const ushort4*)&pp[(size_t)z * NN * UU + idx];
    a0 += bf2f(v.x); a1 += bf2f(v.y); a2 += bf2f(v.z); a3 += bf2f(v.w);
  }
  int s = n % SS, b = n / SS;
  float sm = sent[s * BB + b];
  float4 o;
  o.x = fmaxf(a0, 0.f) * sm; o.y = fmaxf(a1, 0.f) * sm;
  o.z = fmaxf(a2, 0.f) * sm; o.w = fmaxf(a3, 0.f) * sm;
  *(float4*)&out[((size_t)s * BB + b) * UU + u4] = o;
}

extern "C" void kernel_launch(void* const* d_in, const int* in_sizes, int n_in,
                              void* d_out, int out_size, void* d_ws, size_t ws_size,
                              hipStream_t stream) {
  const float* src      = (const float*)d_in[0];
  const float* V_in     = (const float*)d_in[1];
  const float* b_in     = (const float*)d_in[2];
  const float* V_ing    = (const float*)d_in[3];
  const float* b_ing    = (const float*)d_in[4];
  const float* V_out    = (const float*)d_in[5];
  const float* b_out    = (const float*)d_in[6];
  const float* V_outg   = (const float*)d_in[7];
  const float* b_outg   = (const float*)d_in[8];
  const float* W_self   = (const float*)d_in[9];
  const float* W_selfg  = (const float*)d_in[10];
  const int* arc_in     = (const int*)d_in[11];
  const int* arc_out    = (const int*)d_in[12];
  const int* lab_in     = (const int*)d_in[13];
  const int* lab_out    = (const int*)d_in[14];
  const float* mask_in  = (const float*)d_in[15];
  const float* mask_out = (const float*)d_in[16];
  const float* mask_loop= (const float*)d_in[17];
  const float* sent     = (const float*)d_in[18];
  float* out = (float*)d_out;

  char* ws = (char*)d_ws;
  size_t off = 0;
  auto alloc = [&](size_t bytes) -> void* {
    void* p = ws + off;
    off += (bytes + 255) & ~(size_t)255;
    return p;
  };
  __hip_bfloat16* x_bf = (__hip_bfloat16*)alloc((size_t)NN * DD * 2);       // 4 MB
  __hip_bfloat16* Vt   = (__hip_bfloat16*)alloc((size_t)UU * KTOT * 2);     // 4.5 MB
  float* xg_in   = (float*)alloc(NN * 4);
  float* xg_out  = (float*)alloc(NN * 4);
  float* xg_loop = (float*)alloc(NN * 4);
  __hip_bfloat16* Y = (__hip_bfloat16*)alloc((size_t)NN * KTOT * 2);        // 143 MB
  __hip_bfloat16* partial =
      (__hip_bfloat16*)alloc((size_t)KSPLIT * NN * UU * 2);                 // 34 MB

  k_prep<<<NN, 256, 0, stream>>>(src, V_ing, V_outg, W_selfg, x_bf, xg_in, xg_out, xg_loop);
  k_transpose<<<dim3(UU / 32, DD / 32, NSLICE + 1), dim3(32, 8), 0, stream>>>(
      V_in, V_out, W_self, b_in, b_out, Vt);
  k_agg<<<NN, 64, 0, stream>>>(x_bf, xg_in, xg_out, xg_loop, b_ing, b_outg,
                               arc_in, arc_out, lab_in, lab_out,
                               mask_in, mask_out, mask_loop, Y);
  k_gemm<<<dim3(NN / 128, UU / 128, KSPLIT), 256, 0, stream>>>(Y, Vt, partial);
  k_finish<<<NN, 64, 0, stream>>>(partial, sent, out);
}

// Round 6
// 192.363 us; speedup vs baseline: 1.1860x; 1.0961x over previous
//
#include <hip/hip_runtime.h>
#include <hip/hip_bf16.h>

// Problem constants (fixed by the reference).
#define BB 32
#define SS 256
#define DD 256
#define UU 256
#define LL 16
#define DEG 16
#define NN (BB * SS)   // 8192 nodes
#define EE (NN * DEG)  // 131072 edges per branch
#define NSLICE 33      // slice 0 = self-loop, 1..16 = in labels, 17..32 = out labels
#define KMAIN (NSLICE * DD)   // 8448
#define KEXT 256              // ext cols: wsum/bias GEMM trick (33 used, rest 0)
#define KTOT (KMAIN + KEXT)   // 8704 = 34*256
#define KSPLIT 8
#define KS (KTOT / KSPLIT)    // 1088 = 34*32
#define TM 128
#define TN 256

using short8 = __attribute__((ext_vector_type(8))) short;  // 8 bf16 (4 VGPRs)
using f32x4  = __attribute__((ext_vector_type(4))) float;  // MFMA accumulator

// async global->LDS, 16B per lane, LDS dest = wave-uniform base + lane*16
#define GLDS(g, l)                                                        \
  __builtin_amdgcn_global_load_lds(                                       \
      (const __attribute__((address_space(1))) void*)(g),                 \
      (__attribute__((address_space(3))) void*)(l), 16, 0, 0)

__device__ __forceinline__ float bf2f(unsigned short v) {
  union { unsigned u; float f; } t;
  t.u = ((unsigned)v) << 16;
  return t.f;
}
__device__ __forceinline__ unsigned short f2bf(float f) {
  __hip_bfloat16 h = __float2bfloat16(f);
  return *(unsigned short*)&h;
}
__device__ __forceinline__ float sigm(float x) {
  return 1.f / (1.f + __expf(-x));
}

// ---------------------------------------------------------------------------
// K1 (merged): blocks [0,NN): prep (x cast + 3 gate dots).
// blocks [NN, NN+(NSLICE+1)*64): weight transpose + ext bias rows.
// ---------------------------------------------------------------------------
__global__ __launch_bounds__(256) void k_pre(
    const float* __restrict__ src, const float* __restrict__ gin,
    const float* __restrict__ gout, const float* __restrict__ gloop,
    const float* __restrict__ Vin, const float* __restrict__ Vout,
    const float* __restrict__ Wself, const float* __restrict__ b_in,
    const float* __restrict__ b_out,
    __hip_bfloat16* __restrict__ x_bf, float* __restrict__ xg_in,
    float* __restrict__ xg_out, float* __restrict__ xg_loop,
    __hip_bfloat16* __restrict__ Vt) {
  int bid = blockIdx.x;
  if (bid < NN) {
    int n = bid;
    int b = n / SS, s = n % SS;
    int d = threadIdx.x;
    float v = src[(size_t)(s * BB + b) * DD + d];
    x_bf[(size_t)n * DD + d] = __float2bfloat16(v);
    float p0 = v * gin[d], p1 = v * gout[d], p2 = v * gloop[d];
#pragma unroll
    for (int o = 32; o > 0; o >>= 1) {
      p0 += __shfl_down(p0, o);
      p1 += __shfl_down(p1, o);
      p2 += __shfl_down(p2, o);
    }
    __shared__ float r0[4], r1[4], r2[4];
    int w = threadIdx.x >> 6, lane = threadIdx.x & 63;
    if (lane == 0) { r0[w] = p0; r1[w] = p1; r2[w] = p2; }
    __syncthreads();
    if (threadIdx.x == 0) {
      xg_in[n]   = r0[0] + r0[1] + r0[2] + r0[3];
      xg_out[n]  = r1[0] + r1[1] + r1[2] + r1[3];
      xg_loop[n] = r2[0] + r2[1] + r2[2] + r2[3];
    }
    return;
  }
  int t = bid - NN;
  int z = t >> 6;                 // 0..NSLICE
  int rem = t & 63;
  int bx = rem & 7, by = rem >> 3;
  int tid = threadIdx.x;
  int tx = tid & 31, ty = tid >> 5;
  if (z == NSLICE) {              // ext bias rows: Vt[u][KMAIN+j] = bias_all[j][u]
    int u0 = bx * 32, j0 = by * 32;
#pragma unroll
    for (int i = 0; i < 4; i++) {
      int u = u0 + ty + i * 8, j = j0 + tx;
      float v = 0.f;
      if (j >= 1 && j <= LL)         v = b_in[(j - 1) * UU + u];
      else if (j > LL && j < NSLICE) v = b_out[(j - 1 - LL) * UU + u];
      Vt[(size_t)u * KTOT + KMAIN + j] = __float2bfloat16(v);
    }
    return;
  }
  __shared__ float tbuf[32][33];
  const float* srcM = (z == 0) ? Wself
                    : (z <= LL ? Vin  + (size_t)(z - 1)      * DD * UU
                               : Vout + (size_t)(z - 1 - LL) * DD * UU);
  int u0 = bx * 32, d0 = by * 32;
#pragma unroll
  for (int i = 0; i < 4; i++) {
    int dr = ty + i * 8;
    tbuf[dr][tx] = srcM[(size_t)(d0 + dr) * UU + u0 + tx];
  }
  __syncthreads();
#pragma unroll
  for (int i = 0; i < 4; i++) {
    int ur = ty + i * 8;
    Vt[(size_t)(u0 + ur) * KTOT + z * DD + d0 + tx] = __float2bfloat16(tbuf[tx][ur]);
  }
}

// ---------------------------------------------------------------------------
// K3: aggregation, one WAVE per dst node (unchanged from round 5 — proven
// correct; rewrites were neutral). Y[n][slice*256+d]; ext col j = wsum.
// ---------------------------------------------------------------------------
__global__ __launch_bounds__(64) void k_agg(
    const __hip_bfloat16* __restrict__ x,
    const float* __restrict__ xg_in, const float* __restrict__ xg_out,
    const float* __restrict__ xg_loop,
    const float* __restrict__ b_ing, const float* __restrict__ b_outg,
    const int* __restrict__ arc_in, const int* __restrict__ arc_out,
    const int* __restrict__ lab_in, const int* __restrict__ lab_out,
    const float* __restrict__ mask_in, const float* __restrict__ mask_out,
    const float* __restrict__ mask_loop,
    __hip_bfloat16* __restrict__ Y) {
  __shared__ int u_sl[32], u_src[32];
  __shared__ float u_w[32];
  __shared__ int s_sl[32], s_src[32];
  __shared__ float s_w[32];
  __shared__ float s_wsum[NSLICE];
  int n = blockIdx.x, tid = threadIdx.x;
  if (tid < 32) {
    int br = tid >> 4, k = tid & 15;
    int e = n * DEG + k;
    const int* a = br ? arc_out : arc_in;
    int l = (br ? lab_out : lab_in)[e];
    int srcn = a[e] * SS + a[EE + e];
    float g = (br ? xg_out : xg_in)[srcn] + (br ? b_outg : b_ing)[l];
    u_sl[tid] = 1 + br * LL + l;
    u_src[tid] = srcn;
    u_w[tid] = sigm(g) * (br ? mask_out : mask_in)[e];
  }
  __syncthreads();
  if (tid < 32) {
    int my = u_sl[tid];
    int rank = 0;
#pragma unroll
    for (int j = 0; j < 32; j++) {
      int oj = u_sl[j];
      rank += (oj < my || (oj == my && j < tid)) ? 1 : 0;
    }
    s_sl[rank] = my;
    s_src[rank] = u_src[tid];
    s_w[rank] = u_w[tid];
  }
  __syncthreads();

  const unsigned short* xp = (const unsigned short*)x;
  unsigned short* yp = (unsigned short*)Y;
  size_t base = (size_t)n * KTOT;
  int d4 = tid * 4;
  {
    float wl = sigm(xg_loop[n]) * mask_loop[n];
    ushort4 v = *(const ushort4*)&xp[(size_t)n * DD + d4];
    ushort4 o;
    o.x = f2bf(wl * bf2f(v.x)); o.y = f2bf(wl * bf2f(v.y));
    o.z = f2bf(wl * bf2f(v.z)); o.w = f2bf(wl * bf2f(v.w));
    *(ushort4*)&yp[base + d4] = o;
  }
  unsigned long long present = 0ull;
  float a0 = 0.f, a1 = 0.f, a2 = 0.f, a3 = 0.f, ws = 0.f;
#pragma unroll
  for (int e = 0; e < 32; e++) {
    int sl = s_sl[e];
    int srcn = s_src[e];
    float w = s_w[e];
    ushort4 v = *(const ushort4*)&xp[(size_t)srcn * DD + d4];
    a0 += w * bf2f(v.x); a1 += w * bf2f(v.y);
    a2 += w * bf2f(v.z); a3 += w * bf2f(v.w);
    ws += w;
    int slnext = (e < 31) ? s_sl[e + 1] : 999;
    if (sl != slnext) {
      ushort4 o;
      o.x = f2bf(a0); o.y = f2bf(a1); o.z = f2bf(a2); o.w = f2bf(a3);
      *(ushort4*)&yp[base + sl * DD + d4] = o;
      if (tid == 0) s_wsum[sl] = ws;
      present |= (1ull << sl);
      a0 = a1 = a2 = a3 = ws = 0.f;
    }
  }
  ushort4 zero4 = {0, 0, 0, 0};
#pragma unroll
  for (int s = 1; s < NSLICE; s++) {
    if (!((present >> s) & 1ull)) {
      *(ushort4*)&yp[base + s * DD + d4] = zero4;
      if (tid == 0) s_wsum[s] = 0.f;
    }
  }
  __syncthreads();
  {
    ushort4 o;
    unsigned short* op = (unsigned short*)&o;
#pragma unroll
    for (int c = 0; c < 4; c++) {
      int j = d4 + c;
      float v = (j >= 1 && j < NSLICE) ? s_wsum[j] : 0.f;
      op[c] = f2bf(v);
    }
    *(ushort4*)&yp[base + KMAIN + d4] = o;
  }
}

// ---------------------------------------------------------------------------
// K4: bf16 MFMA GEMM, PIPELINED single-barrier K-loop with LDS double buffer.
// Tile 128 rows x 256 cols (full U per block -> A read once). 4 waves, wave w
// owns cols [w*64, w*64+64): 8x4 frags of 16x16x32. Prefetch for iter i+1 is
// issued right after the barrier of iter i, so the next barrier's vmcnt drain
// only waits for latency not hidden by a full compute phase (HBM-cold Y).
// grid (NN/TM, KSPLIT); partial[z][n][u] bf16.
// ---------------------------------------------------------------------------
__global__ __launch_bounds__(256, 2) void k_gemm(
    const __hip_bfloat16* __restrict__ A, const __hip_bfloat16* __restrict__ Bt,
    __hip_bfloat16* __restrict__ partial) {
  __shared__ __align__(16) __hip_bfloat16 As[2][TM * 32];
  __shared__ __align__(16) __hip_bfloat16 Bs[2][TN * 32];
  __hip_bfloat16* P = partial + (size_t)blockIdx.y * NN * UU;
  int kbeg = blockIdx.y * KS;
  int row0 = blockIdx.x * TM;
  int tid = threadIdx.x;
  int w = tid >> 6, lane = tid & 63;
  int lrow = lane & 15, quad = lane >> 4;
  int sr = lane >> 2;          // staging: row within 16-row group
  int sc = (lane & 3) * 8;     // staging: k-offset (elements)

#define STAGE(bufi, k0)                                                     \
  {                                                                         \
    _Pragma("unroll")                                                       \
    for (int t = 0; t < 2; t++) {                                           \
      int rb = (w * 2 + t) * 16;                                            \
      GLDS(&A[(size_t)(row0 + rb + sr) * KTOT + (k0) + sc],                 \
           &As[bufi][rb * 32]);                                             \
    }                                                                       \
    _Pragma("unroll")                                                       \
    for (int t = 0; t < 4; t++) {                                           \
      int rb = (w * 4 + t) * 16;                                            \
      GLDS(&Bt[(size_t)(rb + sr) * KTOT + (k0) + sc], &Bs[bufi][rb * 32]);  \
    }                                                                       \
  }

  STAGE(0, kbeg);
  f32x4 acc[8][4] = {};
  constexpr int NIT = KS / 32;   // 34
  for (int it = 0; it < NIT; it++) {
    int cur = it & 1;
    __syncthreads();             // drains prefetch issued one full iter ago
    if (it + 1 < NIT) STAGE(cur ^ 1, kbeg + (it + 1) * 32);
    short8 af[8], bfr[4];
#pragma unroll
    for (int i = 0; i < 8; i++)
      af[i] = *(const short8*)&As[cur][(i * 16 + lrow) * 32 + quad * 8];
#pragma unroll
    for (int j = 0; j < 4; j++)
      bfr[j] = *(const short8*)&Bs[cur][(w * 64 + j * 16 + lrow) * 32 + quad * 8];
#pragma unroll
    for (int j = 0; j < 4; j++)
#pragma unroll
      for (int i = 0; i < 8; i++)
        acc[i][j] = __builtin_amdgcn_mfma_f32_16x16x32_bf16(af[i], bfr[j], acc[i][j], 0, 0, 0);
  }
#undef STAGE
  // C/D layout (m89/m91): col = lane&15, row = quad*4 + r
#pragma unroll
  for (int i = 0; i < 8; i++)
#pragma unroll
    for (int j = 0; j < 4; j++) {
      int col = w * 64 + j * 16 + lrow;
      int rowb = row0 + i * 16 + quad * 4;
#pragma unroll
      for (int r = 0; r < 4; r++)
        P[(size_t)(rowb + r) * UU + col] = __float2bfloat16(acc[i][j][r]);
    }
}

// ---------------------------------------------------------------------------
// K5: reduce KSPLIT bf16 partials + relu + sent_mask + transpose to out[s,b,u].
// ---------------------------------------------------------------------------
__global__ __launch_bounds__(64) void k_finish(
    const __hip_bfloat16* __restrict__ partial, const float* __restrict__ sent,
    float* __restrict__ out) {
  int n = blockIdx.x, u4 = threadIdx.x * 4;
  size_t idx = (size_t)n * UU + u4;
  const unsigned short* pp = (const unsigned short*)partial;
  float a0 = 0.f, a1 = 0.f, a2 = 0.f, a3 = 0.f;
#pragma unroll
  for (int z = 0; z < KSPLIT; z++) {
    ushort4 v = *(const ushort4*)&pp[(size_t)z * NN * UU + idx];
    a0 += bf2f(v.x); a1 += bf2f(v.y); a2 += bf2f(v.z); a3 += bf2f(v.w);
  }
  int s = n % SS, b = n / SS;
  float sm = sent[s * BB + b];
  float4 o;
  o.x = fmaxf(a0, 0.f) * sm; o.y = fmaxf(a1, 0.f) * sm;
  o.z = fmaxf(a2, 0.f) * sm; o.w = fmaxf(a3, 0.f) * sm;
  *(float4*)&out[((size_t)s * BB + b) * UU + u4] = o;
}

extern "C" void kernel_launch(void* const* d_in, const int* in_sizes, int n_in,
                              void* d_out, int out_size, void* d_ws, size_t ws_size,
                              hipStream_t stream) {
  const float* src      = (const float*)d_in[0];
  const float* V_in     = (const float*)d_in[1];
  const float* b_in     = (const float*)d_in[2];
  const float* V_ing    = (const float*)d_in[3];
  const float* b_ing    = (const float*)d_in[4];
  const float* V_out    = (const float*)d_in[5];
  const float* b_out    = (const float*)d_in[6];
  const float* V_outg   = (const float*)d_in[7];
  const float* b_outg   = (const float*)d_in[8];
  const float* W_self   = (const float*)d_in[9];
  const float* W_selfg  = (const float*)d_in[10];
  const int* arc_in     = (const int*)d_in[11];
  const int* arc_out    = (const int*)d_in[12];
  const int* lab_in     = (const int*)d_in[13];
  const int* lab_out    = (const int*)d_in[14];
  const float* mask_in  = (const float*)d_in[15];
  const float* mask_out = (const float*)d_in[16];
  const float* mask_loop= (const float*)d_in[17];
  const float* sent     = (const float*)d_in[18];
  float* out = (float*)d_out;

  char* ws = (char*)d_ws;
  size_t off = 0;
  auto alloc = [&](size_t bytes) -> void* {
    void* p = ws + off;
    off += (bytes + 255) & ~(size_t)255;
    return p;
  };
  __hip_bfloat16* x_bf = (__hip_bfloat16*)alloc((size_t)NN * DD * 2);       // 4 MB
  __hip_bfloat16* Vt   = (__hip_bfloat16*)alloc((size_t)UU * KTOT * 2);     // 4.5 MB
  float* xg_in   = (float*)alloc(NN * 4);
  float* xg_out  = (float*)alloc(NN * 4);
  float* xg_loop = (float*)alloc(NN * 4);
  __hip_bfloat16* Y = (__hip_bfloat16*)alloc((size_t)NN * KTOT * 2);        // 143 MB
  __hip_bfloat16* partial =
      (__hip_bfloat16*)alloc((size_t)KSPLIT * NN * UU * 2);                 // 34 MB

  k_pre<<<NN + (NSLICE + 1) * 64, 256, 0, stream>>>(
      src, V_ing, V_outg, W_selfg, V_in, V_out, W_self, b_in, b_out,
      x_bf, xg_in, xg_out, xg_loop, Vt);
  k_agg<<<NN, 64, 0, stream>>>(x_bf, xg_in, xg_out, xg_loop, b_ing, b_outg,
                               arc_in, arc_out, lab_in, lab_out,
                               mask_in, mask_out, mask_loop, Y);
  k_gemm<<<dim3(NN / TM, KSPLIT), 256, 0, stream>>>(Y, Vt, partial);
  k_finish<<<NN, 64, 0, stream>>>(partial, sent, out);
}